// Round 24
// baseline (75.072 us; speedup 1.0000x reference)
//
#include <hip/hip_runtime.h>
#include <hip/hip_fp16.h>
#include <math.h>

#define BATCH 8
#define H 480
#define W 640
#define HW (H * W)

// ---- geometry: 16 steps fused, 512-thr blocks sized for 2 blocks/CU ----
#define PS 16                 // fused steps (= total)
#define PTX 96                // output tile width
#define PTY 48                // output tile height
#define PRX 128               // region cols = PTX + 2*PS (= 64 lanes x 2)
#define PRY 80                // region rows = PTY + 2*PS = NSTRIP * RPT
#define NT 512                // 8 waves; wave = strip, lane = col pair
#define RPT 10                // rows per thread (held in registers)
#define NSTRIP 8
#define NBX 7                 // ceil(640/96)
#define NBY 10                // 480/48
#define NBLK (NBX * NBY * BATCH)   // 560 = 8 XCDs x 70 (70 = one image)
#define NXCD 8
#define BPX (NBLK / NXCD)     // 70 blocks per XCD = exactly one batch image

typedef __half2 h2;

__device__ __forceinline__ unsigned h2u(h2 v) { return __builtin_bit_cast(unsigned, v); }
__device__ __forceinline__ h2 u2h(unsigned u) { return __builtin_bit_cast(h2, u); }

// DPP wave-wide shifts: lane i <- lane i-1 (0x138) / lane i+1 (0x130);
// shifted-in lanes get 0 (region rim: trapezoid-stale-safe / w=0 px).
__device__ __forceinline__ h2 dppLh(h2 v) {
    return u2h((unsigned)__builtin_amdgcn_update_dpp(
        0, (int)h2u(v), 0x138, 0xF, 0xF, false));
}
__device__ __forceinline__ h2 dppRh(h2 v) {
    return u2h((unsigned)__builtin_amdgcn_update_dpp(
        0, (int)h2u(v), 0x130, 0xF, 0xF, false));
}
// {lo = b.hi, hi = a.lo}  (v_alignbit_b32 a, b, 16)
__device__ __forceinline__ h2 algn(h2 a, h2 b) {
    return u2h(__builtin_amdgcn_alignbit(h2u(a), h2u(b), 16));
}

struct Win { h2 L, C, R; };
__device__ __forceinline__ Win mkwin(h2 c) {
    Win w;
    w.C = c;
    w.L = algn(c, dppLh(c));
    w.R = algn(dppRh(c), c);
    return w;
}

// 9-tap packed update for one output row: 9 x v_pk_fma_f16.
__device__ __forceinline__ h2 rowpx(const h2* wt, h2 bias, Win T, Win M, Win B) {
    h2 a = bias;
    a = __hfma2(wt[0], T.L, a);
    a = __hfma2(wt[1], T.C, a);
    a = __hfma2(wt[2], T.R, a);
    a = __hfma2(wt[3], M.L, a);
    a = __hfma2(wt[4], M.C, a);
    a = __hfma2(wt[5], M.R, a);
    a = __hfma2(wt[6], B.L, a);
    a = __hfma2(wt[7], B.C, a);
    a = __hfma2(wt[8], B.R, a);
    return a;
}

// r22 math + XCD swizzle, in 512-thread blocks sized for 2-block/CU
// co-residency: block B's guided-load prologue overlaps block A's 16-step
// VALU phase on the same CU. 560 = 8 x 70 where 70 = one image's tiles ->
// each XCD's L2 serves one image (halo re-reads are L2 hits). Registers
// ~110 persistent u32/wave (<=128 incl. temps) under launch_bounds(512,4).
__global__ __launch_bounds__(NT, 4) void prop16_kernel(
    const float* __restrict__ guided,   // (B,9,H,W)
    const float* __restrict__ x,        // (B,1,H,W)
    const float* __restrict__ sparse,   // (B,1,H,W)
    float* __restrict__ xout)           // (B,1,H,W)
{
    __shared__ unsigned bnd[2][NSTRIP][2][64];   // 8,192 B

    const int tid  = threadIdx.x;
    const int lane = tid & 63;          // col pair (0..63)
    const int strip = tid >> 6;         // wave id = strip (0..7)
    const int r0 = strip * RPT;

    // XCD swizzle: slot -> logical block (bijective, 560 = 8 * 70)
    const int slot = blockIdx.x;
    const int lb = (slot & (NXCD - 1)) * BPX + (slot >> 3);
    const int b  = lb / (NBX * NBY);
    const int rem = lb - b * (NBX * NBY);
    const int by = rem / NBX;
    const int bx = rem - by * NBX;

    const int bx0 = bx * PTX, by0 = by * PTY;
    const int gx0 = bx0 - PS, gy0 = by0 - PS;
    const size_t ob = (size_t)b * HW;
    const int gx = gx0 + 2 * lane;
    const bool cok = (gx >= 0) && (gx < W);

    // ---- per-row: load x, inline softmax + mask fold -> registers ----
    h2 xr[RPT];         // x state (even,odd col pair), fp16
    h2 wt[RPT][9];      // tap weights
    h2 bs[RPT];         // bias (mask * x0)
#pragma unroll
    for (int i = 0; i < RPT; ++i) {
        const int gy = gy0 + r0 + i;
        if (cok && gy >= 0 && gy < H) {
            const size_t p = (size_t)gy * W + gx;
            const float2 xf = *(const float2*)(x + ob + p);
            xr[i] = __floats2half2_rn(xf.x, xf.y);
            float2 g[9];
            float se = 0.f, so = 0.f;
#pragma unroll
            for (int k = 0; k < 9; ++k) {
                g[k] = *(const float2*)(guided + ((size_t)(b * 9 + k)) * HW + p);
                g[k].x = __expf(g[k].x); se += g[k].x;
                g[k].y = __expf(g[k].y); so += g[k].y;
            }
            const float2 sv = *(const float2*)(sparse + ob + p);
            const float maske = (sv.x > 0.f) ? 1.f : 0.f;
            const float masko = (sv.y > 0.f) ? 1.f : 0.f;
            const float sce = (1.f - maske) * __builtin_amdgcn_rcpf(se);
            const float sco = (1.f - masko) * __builtin_amdgcn_rcpf(so);
#pragma unroll
            for (int k = 0; k < 9; ++k)
                wt[i][k] = __floats2half2_rn(g[k].x * sce, g[k].y * sco);
            bs[i] = __floats2half2_rn(maske * xf.x, masko * xf.y);
        } else {
            xr[i] = __floats2half2_rn(0.f, 0.f);
#pragma unroll
            for (int k = 0; k < 9; ++k) wt[i][k] = __floats2half2_rn(0.f, 0.f);
            bs[i] = __floats2half2_rn(0.f, 0.f);
        }
    }
    // publish initial boundary rows (state 0 lives in bnd[0])
    bnd[0][strip][0][lane] = h2u(xr[0]);
    bnd[0][strip][1][lane] = h2u(xr[RPT - 1]);
    __syncthreads();     // bnd[0] visible to neighbor strips

    // ---- 16 Jacobi steps; interior in registers, boundaries via LDS ----
    for (int t = 0; t < PS; ++t) {
        const int cur = t & 1, nxt = cur ^ 1;
        h2 tp, bp;
        if (strip > 0) tp = u2h(bnd[cur][strip - 1][1][lane]);
        else           tp = xr[0];
        if (strip < NSTRIP - 1) bp = u2h(bnd[cur][strip + 1][0][lane]);
        else                    bp = xr[RPT - 1];
        Win T = mkwin(tp);
        Win M = mkwin(xr[0]);
        h2 nfirst;
#pragma unroll
        for (int r = 0; r < RPT; ++r) {
            const Win B = mkwin((r < RPT - 1) ? xr[r + 1] : bp);
            const h2 n = rowpx(wt[r], bs[r], T, M, B);
            if (r == 0) nfirst = n;
            xr[r] = n;
            T = M; M = B;
        }
        bnd[nxt][strip][0][lane] = h2u(nfirst);
        bnd[nxt][strip][1][lane] = h2u(xr[RPT - 1]);
        __syncthreads();
    }

    // ---- write own tile pixels straight from registers (f32 out) ----
    if ((2 * lane) >= PS && (2 * lane) < PS + PTX && gx < W) {
#pragma unroll
        for (int i = 0; i < RPT; ++i) {
            const int rr = r0 + i;
            const int gy = gy0 + rr;
            if (rr >= PS && rr < PS + PTY && gy < H) {
                const float2 o = __half22float2(xr[i]);
                *(float2*)(xout + ob + (size_t)gy * W + gx) = o;
            }
        }
    }
}

extern "C" void kernel_launch(void* const* d_in, const int* in_sizes, int n_in,
                              void* d_out, int out_size, void* d_ws, size_t ws_size,
                              hipStream_t stream) {
    const float* guided = (const float*)d_in[0];
    const float* x      = (const float*)d_in[1];
    const float* sparse = (const float*)d_in[2];
    float* out = (float*)d_out;

    dim3 blk(NT, 1, 1);
    dim3 grd(NBLK, 1, 1);   // 560 blocks, 1D for explicit XCD swizzle
    prop16_kernel<<<grd, blk, 0, stream>>>(guided, x, sparse, out);
}

// Round 25
// 52.335 us; speedup vs baseline: 1.4345x; 1.4345x over previous
//
#include <hip/hip_runtime.h>
#include <hip/hip_fp16.h>
#include <math.h>

#define BATCH 8
#define H 480
#define W 640
#define HW (H * W)

// ---- single-launch geometry (r15): all 16 steps fused, 224 blocks ----
#define PS 16                 // fused steps (= total)
#define PTX 96                // output tile width
#define PTY 128               // output tile height
#define PRX 128               // region cols = PTX + 2*PS (= 64 lanes x 2)
#define PRY 160               // region rows = PTY + 2*PS = NSTRIP * RPT
#define NT 1024               // 16 waves; wave = strip, lane = col pair
#define RPT 10                // rows per thread (held in registers)
#define NSTRIP 16
#define NBX 7                 // ceil(640/96)
#define NBY 4                 // ceil(480/128)
#define NBLK (NBX * NBY * BATCH)   // 224 = 8 XCDs x 28
#define NXCD 8
#define BPX (NBLK / NXCD)     // 28 blocks per XCD = one batch image

typedef __half2 h2;

__device__ __forceinline__ unsigned h2u(h2 v) { return __builtin_bit_cast(unsigned, v); }
__device__ __forceinline__ h2 u2h(unsigned u) { return __builtin_bit_cast(h2, u); }

// DPP wave-wide shifts: lane i <- lane i-1 (0x138) / lane i+1 (0x130);
// shifted-in lanes get 0 (region rim: trapezoid-stale-safe / w=0 px).
__device__ __forceinline__ h2 dppLh(h2 v) {
    return u2h((unsigned)__builtin_amdgcn_update_dpp(
        0, (int)h2u(v), 0x138, 0xF, 0xF, false));
}
__device__ __forceinline__ h2 dppRh(h2 v) {
    return u2h((unsigned)__builtin_amdgcn_update_dpp(
        0, (int)h2u(v), 0x130, 0xF, 0xF, false));
}
// {lo = b.hi, hi = a.lo}  (v_alignbit_b32 a, b, 16)
__device__ __forceinline__ h2 algn(h2 a, h2 b) {
    return u2h(__builtin_amdgcn_alignbit(h2u(a), h2u(b), 16));
}

struct Win { h2 L, C, R; };
__device__ __forceinline__ Win mkwin(h2 c) {
    Win w;
    w.C = c;
    w.L = algn(c, dppLh(c));
    w.R = algn(dppRh(c), c);
    return w;
}

// 9-tap packed update for one output row: 9 x v_pk_fma_f16.
__device__ __forceinline__ h2 rowpx(const h2* wt, h2 bias, Win T, Win M, Win B) {
    h2 a = bias;
    a = __hfma2(wt[0], T.L, a);
    a = __hfma2(wt[1], T.C, a);
    a = __hfma2(wt[2], T.R, a);
    a = __hfma2(wt[3], M.L, a);
    a = __hfma2(wt[4], M.C, a);
    a = __hfma2(wt[5], M.R, a);
    a = __hfma2(wt[6], B.L, a);
    a = __hfma2(wt[7], B.C, a);
    a = __hfma2(wt[8], B.R, a);
    return a;
}

// Best-known configuration (round 22): register-resident rows + packed-fp16
// math + XCD-aware block swizzle + lean softmax (no max-subtraction: guided
// ~ N(0,1), exp range safe in f32; native rcp feeding fp16 weights).
__global__ __launch_bounds__(NT) void prop16_kernel(
    const float* __restrict__ guided,   // (B,9,H,W)
    const float* __restrict__ x,        // (B,1,H,W)
    const float* __restrict__ sparse,   // (B,1,H,W)
    float* __restrict__ xout)           // (B,1,H,W)
{
    __shared__ unsigned bnd[2][NSTRIP][2][64];   // 16,384 B

    const int tid  = threadIdx.x;
    const int lane = tid & 63;          // col pair (0..63)
    const int strip = tid >> 6;         // wave id = strip (0..15)
    const int r0 = strip * RPT;

    // XCD swizzle: slot -> logical block (bijective, 224 = 8 * 28)
    const int slot = blockIdx.x;
    const int lb = (slot & (NXCD - 1)) * BPX + (slot >> 3);
    const int b  = lb / (NBX * NBY);
    const int rem = lb - b * (NBX * NBY);
    const int by = rem / NBX;
    const int bx = rem - by * NBX;

    const int bx0 = bx * PTX, by0 = by * PTY;
    const int gx0 = bx0 - PS, gy0 = by0 - PS;
    const size_t ob = (size_t)b * HW;
    const int gx = gx0 + 2 * lane;
    const bool cok = (gx >= 0) && (gx < W);

    // ---- per-row: load x, inline softmax + mask fold -> registers ----
    h2 xr[RPT];         // x state (even,odd col pair), fp16
    h2 wt[RPT][9];      // tap weights
    h2 bs[RPT];         // bias (mask * x0)
#pragma unroll
    for (int i = 0; i < RPT; ++i) {
        const int gy = gy0 + r0 + i;
        if (cok && gy >= 0 && gy < H) {
            const size_t p = (size_t)gy * W + gx;
            const float2 xf = *(const float2*)(x + ob + p);
            xr[i] = __floats2half2_rn(xf.x, xf.y);
            float2 g[9];
            float se = 0.f, so = 0.f;
#pragma unroll
            for (int k = 0; k < 9; ++k) {
                g[k] = *(const float2*)(guided + ((size_t)(b * 9 + k)) * HW + p);
                g[k].x = __expf(g[k].x); se += g[k].x;
                g[k].y = __expf(g[k].y); so += g[k].y;
            }
            const float2 sv = *(const float2*)(sparse + ob + p);
            const float maske = (sv.x > 0.f) ? 1.f : 0.f;
            const float masko = (sv.y > 0.f) ? 1.f : 0.f;
            const float sce = (1.f - maske) * __builtin_amdgcn_rcpf(se);
            const float sco = (1.f - masko) * __builtin_amdgcn_rcpf(so);
#pragma unroll
            for (int k = 0; k < 9; ++k)
                wt[i][k] = __floats2half2_rn(g[k].x * sce, g[k].y * sco);
            bs[i] = __floats2half2_rn(maske * xf.x, masko * xf.y);
        } else {
            xr[i] = __floats2half2_rn(0.f, 0.f);
#pragma unroll
            for (int k = 0; k < 9; ++k) wt[i][k] = __floats2half2_rn(0.f, 0.f);
            bs[i] = __floats2half2_rn(0.f, 0.f);
        }
    }
    // publish initial boundary rows (state 0 lives in bnd[0])
    bnd[0][strip][0][lane] = h2u(xr[0]);
    bnd[0][strip][1][lane] = h2u(xr[RPT - 1]);
    __syncthreads();     // bnd[0] visible to neighbor strips

    // ---- 16 Jacobi steps; interior in registers, boundaries via LDS ----
    for (int t = 0; t < PS; ++t) {
        const int cur = t & 1, nxt = cur ^ 1;
        h2 tp, bp;
        if (strip > 0) tp = u2h(bnd[cur][strip - 1][1][lane]);
        else           tp = xr[0];
        if (strip < NSTRIP - 1) bp = u2h(bnd[cur][strip + 1][0][lane]);
        else                    bp = xr[RPT - 1];
        Win T = mkwin(tp);
        Win M = mkwin(xr[0]);
        h2 nfirst;
#pragma unroll
        for (int r = 0; r < RPT; ++r) {
            const Win B = mkwin((r < RPT - 1) ? xr[r + 1] : bp);
            const h2 n = rowpx(wt[r], bs[r], T, M, B);
            if (r == 0) nfirst = n;
            xr[r] = n;
            T = M; M = B;
        }
        bnd[nxt][strip][0][lane] = h2u(nfirst);
        bnd[nxt][strip][1][lane] = h2u(xr[RPT - 1]);
        __syncthreads();
    }

    // ---- write own tile pixels straight from registers (f32 out) ----
    if ((2 * lane) >= PS && (2 * lane) < PS + PTX && gx < W) {
#pragma unroll
        for (int i = 0; i < RPT; ++i) {
            const int rr = r0 + i;
            const int gy = gy0 + rr;
            if (rr >= PS && rr < PS + PTY && gy < H) {
                const float2 o = __half22float2(xr[i]);
                *(float2*)(xout + ob + (size_t)gy * W + gx) = o;
            }
        }
    }
}

extern "C" void kernel_launch(void* const* d_in, const int* in_sizes, int n_in,
                              void* d_out, int out_size, void* d_ws, size_t ws_size,
                              hipStream_t stream) {
    const float* guided = (const float*)d_in[0];
    const float* x      = (const float*)d_in[1];
    const float* sparse = (const float*)d_in[2];
    float* out = (float*)d_out;

    dim3 blk(NT, 1, 1);
    dim3 grd(NBLK, 1, 1);   // 224 blocks, 1D for explicit XCD swizzle
    prop16_kernel<<<grd, blk, 0, stream>>>(guided, x, sparse, out);
}